// Round 7
// baseline (324.757 us; speedup 1.0000x reference)
//
#include <hip/hip_runtime.h>
#include <cstddef>

// Problem constants: B=32, N=4096, D=256, K=8 slots, S=16, H=128, 3 iters.

typedef unsigned short ushort_t;
typedef __attribute__((ext_vector_type(8))) short short8;   // 8 bf16 = 4 VGPRs
typedef __attribute__((ext_vector_type(4))) float f32x4;

__device__ __forceinline__ float sigmoid_f(float x){ return 1.f/(1.f+__expf(-x)); }
__device__ __forceinline__ float tanh_f(float x){ return 1.f - 2.f/(__expf(2.f*x)+1.f); }

// fp32 -> bf16 (RNE), as raw bits (weights + mt consistency)
__device__ __forceinline__ ushort_t f2bf(float x){
  unsigned u = __float_as_uint(x);
  return (ushort_t)((u + 0x7FFFu + ((u>>16)&1u)) >> 16);
}
__device__ __forceinline__ float bf2f(ushort_t b){
  return __uint_as_float(((unsigned)b) << 16);
}
// truncation hi/lo split (cheap: AND/SUB/SHR), combined rel err ~2^-17
__device__ __forceinline__ void split_bf(float v, short& hi, short& lo){
  unsigned u = __float_as_uint(v);
  hi = (short)(u >> 16);
  float hf = __uint_as_float(u & 0xFFFF0000u);
  lo = (short)(__float_as_uint(v - hf) >> 16);
}

// raw scope-bypassing poll: fresh read from the coherence point each call,
// no L1/L2 invalidate instructions (unlike an ACQUIRE atomic load).
__device__ __forceinline__ unsigned ld_cohpt(const unsigned* p){
  unsigned v;
  asm volatile("global_load_dword %0, %1, off sc0 sc1\n\t"
               "s_waitcnt vmcnt(0)"
               : "=v"(v) : "v"(p) : "memory");
  return v;
}
// agent-scope relaxed store/load: sc0/sc1 cache-bypass straight to/from the
// coherence point (validated passing in R2/R4/R5).
__device__ __forceinline__ void st_agent(float* p, float v){
  __hip_atomic_store(p, v, __ATOMIC_RELAXED, __HIP_MEMORY_SCOPE_AGENT);
}
__device__ __forceinline__ float ld_agent(const float* p){
  return __hip_atomic_load(p, __ATOMIC_RELAXED, __HIP_MEMORY_SCOPE_AGENT);
}

// ---------------- K0: prep (bf16-split weights, init slots, q1, zeros) -----
__global__ __launch_bounds__(256) void k_prep(
    const float* __restrict__ lnw, const float* __restrict__ lnb,
    const float* __restrict__ wk, const float* __restrict__ wv,
    const float* __restrict__ init_slots,
    const float* __restrict__ ln_s_w, const float* __restrict__ ln_s_b,
    const float* __restrict__ wq,
    ushort_t* __restrict__ Wh, ushort_t* __restrict__ Wl,
    float* __restrict__ mt,
    float* __restrict__ qbuf, float* __restrict__ upd, float* __restrict__ Abuf,
    unsigned* __restrict__ barp,
    float* __restrict__ slots_out)
{
  int t = threadIdx.x;
  int i = blockIdx.x*256 + t;          // 32*256 == 8192 exactly
  {
    int s = i >> 8, d = i & 255;
    float w = (s < 16) ? wk[s*256+d] : wv[(s-16)*256+d];
    float w0 = lnw[d]*w;
    ushort_t hb = f2bf(w0);
    ushort_t lb = f2bf(w0 - bf2f(hb));
    Wh[i] = hb; Wl[i] = lb;
  }
  if (blockIdx.x != 0) return;
  // m[s] from QUANTIZED weights; t[s] exact fp32
  {
    int s = t >> 3, j = t & 7;
    float m = 0.f, tv = 0.f;
    for (int d = j; d < 256; d += 8) {
      float w = (s < 16) ? wk[s*256+d] : wv[(s-16)*256+d];
      float w0 = lnw[d]*w;
      ushort_t hb = f2bf(w0);
      float hf = bf2f(hb);
      float lf = bf2f(f2bf(w0 - hf));
      m  += hf + lf;
      tv  = fmaf(lnb[d], w, tv);
    }
    m += __shfl_xor(m,1);  m += __shfl_xor(m,2);  m += __shfl_xor(m,4);
    tv += __shfl_xor(tv,1); tv += __shfl_xor(tv,2); tv += __shfl_xor(tv,4);
    if (j == 0) { mt[s] = m; mt[32+s] = tv; }
  }
  #pragma unroll
  for (int j2 = 0; j2 < 16; ++j2) {
    slots_out[t*16+j2] = init_slots[t*16+j2];
    upd[t*16+j2] = 0.f;              // legacy fallback needs these zeroed
  }
  Abuf[t] = 0.f;
  // barrier counters for k_iter (ws is re-poisoned every replay -> re-zero)
  for (int i2 = t; i2 < 3072; i2 += 256) barp[i2] = 0u;
  // q for iteration 1: thread t = (b,k) row
  float sl[16];
  #pragma unroll
  for (int j2 = 0; j2 < 16; ++j2) sl[j2] = init_slots[t*16+j2];
  float mu = 0.f;
  #pragma unroll
  for (int j2 = 0; j2 < 16; ++j2) mu += sl[j2];
  mu *= (1.f/16.f);
  float var = 0.f;
  #pragma unroll
  for (int j2 = 0; j2 < 16; ++j2) { float d = sl[j2]-mu; var = fmaf(d,d,var); }
  var *= (1.f/16.f);
  float rstd = rsqrtf(var + 1e-5f);
  float y[16];
  #pragma unroll
  for (int j2 = 0; j2 < 16; ++j2) y[j2] = (sl[j2]-mu)*rstd*ln_s_w[j2] + ln_s_b[j2];
  #pragma unroll
  for (int tq = 0; tq < 16; ++tq) {
    float q = 0.f;
    #pragma unroll
    for (int s2 = 0; s2 < 16; ++s2) q = fmaf(y[s2], wq[tq*16+s2], q);
    qbuf[t*16+tq] = q;
  }
}

// ---------------- K1: fused LayerNorm + K/V projection (PROVEN shape) ------
// 2048 blocks x 64 rows, 4 blocks/CU, 33.8 KB LDS -- the best projection
// measured across all sessions (~30us). Unchanged from the verified kernel.
__global__ __launch_bounds__(256, 4) void k_proj(
    const float* __restrict__ x, const ushort_t* __restrict__ Wh,
    const ushort_t* __restrict__ Wl, const float* __restrict__ mt,
    float* __restrict__ kout, float* __restrict__ vout)
{
  __shared__ ushort_t wlds[64*264];
  int t = threadIdx.x;
  int lane = t & 63;
  int p = __builtin_amdgcn_readfirstlane(t >> 6);
  int m = lane & 15, quad = lane >> 4;
  int r0 = blockIdx.x*64;
  {
    const unsigned* srcH = (const unsigned*)Wh;
    const unsigned* srcL = (const unsigned*)Wl;
    unsigned* dst = (unsigned*)wlds;
    #pragma unroll
    for (int i0 = 0; i0 < 8192; i0 += 256) {
      int i = i0 + t;
      int r = i >> 7, w = i & 127;
      unsigned v = (r < 32) ? srcH[r*128 + w] : srcL[(r-32)*128 + w];
      dst[r*132 + w] = v;
    }
  }
  __syncthreads();

  const ushort_t* rhk = wlds + (size_t)m*264 + quad*8;
  const ushort_t* rhv = wlds + (size_t)(16+m)*264 + quad*8;
  const ushort_t* rlk = wlds + (size_t)(32+m)*264 + quad*8;
  const ushort_t* rlv = wlds + (size_t)(48+m)*264 + quad*8;

  const float* xr = x + (size_t)(r0 + p*16 + m)*256 + quad*8;

  f32x4 acck = {0.f,0.f,0.f,0.f}, accv = {0.f,0.f,0.f,0.f};
  float sum = 0.f, sumsq = 0.f;

  #pragma unroll
  for (int kk = 0; kk < 8; ++kk) {
    float4 a0 = *(const float4*)(xr + kk*32);
    float4 a1 = *(const float4*)(xr + kk*32 + 4);
    short8 bh_k = *(const short8*)(rhk + kk*32);
    short8 bh_v = *(const short8*)(rhv + kk*32);
    short8 bl_k = *(const short8*)(rlk + kk*32);
    short8 bl_v = *(const short8*)(rlv + kk*32);
    float xv[8] = {a0.x,a0.y,a0.z,a0.w, a1.x,a1.y,a1.z,a1.w};
    short8 ah, al;
    #pragma unroll
    for (int j = 0; j < 8; ++j) {
      float v = xv[j];
      sum += v; sumsq = fmaf(v, v, sumsq);
      short h_, l_;
      split_bf(v, h_, l_);
      ah[j] = h_; al[j] = l_;
    }
    acck = __builtin_amdgcn_mfma_f32_16x16x32_bf16(ah, bh_k, acck, 0, 0, 0);
    accv = __builtin_amdgcn_mfma_f32_16x16x32_bf16(ah, bh_v, accv, 0, 0, 0);
    acck = __builtin_amdgcn_mfma_f32_16x16x32_bf16(al, bh_k, acck, 0, 0, 0);
    accv = __builtin_amdgcn_mfma_f32_16x16x32_bf16(al, bh_v, accv, 0, 0, 0);
    acck = __builtin_amdgcn_mfma_f32_16x16x32_bf16(ah, bl_k, acck, 0, 0, 0);
    accv = __builtin_amdgcn_mfma_f32_16x16x32_bf16(ah, bl_v, accv, 0, 0, 0);
  }

  sum   += __shfl_xor(sum, 16);  sum   += __shfl_xor(sum, 32);
  sumsq += __shfl_xor(sumsq, 16); sumsq += __shfl_xor(sumsq, 32);

  float mtk  = mt[m],    mtv  = mt[16+m];
  float mtkb = mt[32+m], mtvb = mt[48+m];
  #pragma unroll
  for (int r = 0; r < 4; ++r) {
    int row = quad*4 + r;
    float s_ = __shfl(sum,   row);
    float q_ = __shfl(sumsq, row);
    float mu = s_*(1.f/256.f);
    float var = q_*(1.f/256.f) - mu*mu;
    float rstd = rsqrtf(var + 1e-5f);
    float ok = fmaf(rstd, acck[r] - mu*mtk, mtkb);
    float ov = fmaf(rstd, accv[r] - mu*mtv, mtvb);
    size_t grow = (size_t)(r0 + p*16 + row)*16 + m;
    kout[grow] = ok;
    vout[grow] = ov;
  }
}

// ---------------- K2: all 3 iterations in one kernel -----------------------
// 512 blocks = (b,nc); 52.8 KB LDS -> 3 blocks/CU. Reads kproj/vproj ONCE
// (L3-hot from k_proj), runs 3x(attn -> per-b barrier -> slice-reduce ->
// redundant GRU). Replaces 6 legacy dispatches (~50us) while avoiding the
// mega kernel's low-occupancy proj serialization (R5 lesson: wall = ~205us
// harness const + kernel-sum; minimize the SUM with the best per-phase
// shapes). Iteration body is R5's verified structure verbatim. R6 audit:
// no hang-capable construct (bounded spin; all LDS/global indices bounded);
// R6 container failure attributed to infra (same error as R3, whose logic
// passed in R4). Spin bound tightened to 2^16 (~14ms worst case).
#define IT_VT 0                    // ushort vt[32*264] = 16896 B
#define IT_PT 16896                // ushort pt[16*264] =  8448 B
#define IT_QS 25344                // float qs[128]     =   512 B
#define IT_SL 25856                // float sslots[128] =   512 B
#define IT_AP 26368                // float apart[32]   =   128 B
#define IT_UL 26496                // float ulds[128]   =   512 B
#define IT_GW 27008                // gru/mlp weights   = 25792 B
#define IT_BYTES 52800             // -> 3 blocks/CU (163840/52800 = 3.1)

__global__ __launch_bounds__(256, 3) void k_iter(
    const float* __restrict__ kproj, const float* __restrict__ vproj,
    const float* __restrict__ qbuf, const float* __restrict__ init_slots,
    float* __restrict__ updp, float* __restrict__ Asum,
    unsigned* __restrict__ barp,
    float* __restrict__ slots_out, float* __restrict__ attn_out,
    const float* __restrict__ w_ih, const float* __restrict__ w_hh,
    const float* __restrict__ b_ih, const float* __restrict__ b_hh,
    const float* __restrict__ mlp_w1, const float* __restrict__ mlp_b1,
    const float* __restrict__ mlp_w2, const float* __restrict__ mlp_b2,
    const float* __restrict__ ln_m_w, const float* __restrict__ ln_m_b,
    const float* __restrict__ ln_s_w, const float* __restrict__ ln_s_b,
    const float* __restrict__ wq)
{
  __shared__ __align__(16) unsigned char smem[IT_BYTES];
  ushort_t* vt     = (ushort_t*)(smem + IT_VT);
  ushort_t* pt     = (ushort_t*)(smem + IT_PT);
  float*    qs     = (float*)(smem + IT_QS);
  float*    sslots = (float*)(smem + IT_SL);
  float*    apart  = (float*)(smem + IT_AP);
  float*    ulds   = (float*)(smem + IT_UL);
  float*    s_wih  = (float*)(smem + IT_GW);
  float*    s_whh  = s_wih + 48*17;
  float*    s_w1   = s_whh + 48*17;
  float*    s_w2   = s_w1 + 128*17;
  float*    s_bih  = s_w2 + 16*129;
  float*    s_bhh  = s_bih + 48;
  float*    s_b1   = s_bhh + 48;
  float*    s_b2   = s_b1 + 128;
  float*    s_lnmw = s_b2 + 16;
  float*    s_lnmb = s_lnmw + 16;
  float*    s_lnsw = s_lnmb + 16;
  float*    s_lnsb = s_lnsw + 16;
  float*    s_wq   = s_lnsb + 16;

  int t = threadIdx.x;
  int lane = t & 63;
  int w = t >> 6;
  int b  = blockIdx.x >> 4;
  int nc = blockIdx.x & 15;
  int n0 = nc << 8;

  // ---- stage: k/v rows (once), GRU/MLP weights, q1, slots ----
  const float* kr = kproj + ((size_t)(b*4096 + n0 + t))*16;
  const float* vr = vproj + ((size_t)(b*4096 + n0 + t))*16;
  float kv[16], vv[16];
  #pragma unroll
  for (int j = 0; j < 16; j += 4) {
    float4 f = *(const float4*)(kr+j);
    kv[j]=f.x; kv[j+1]=f.y; kv[j+2]=f.z; kv[j+3]=f.w;
    float4 g = *(const float4*)(vr+j);
    vv[j]=g.x; vv[j+1]=g.y; vv[j+2]=g.z; vv[j+3]=g.w;
  }
  #pragma unroll
  for (int s = 0; s < 16; ++s) {
    short h_, l_;
    split_bf(vv[s], h_, l_);
    vt[s*264 + t]      = (ushort_t)h_;
    vt[(16+s)*264 + t] = (ushort_t)l_;
  }
  for (int i = t; i < 768; i += 256) {
    int g = i >> 4, j = i & 15;
    s_wih[g*17+j] = w_ih[i];
    s_whh[g*17+j] = w_hh[i];
  }
  for (int i = t; i < 2048; i += 256) {
    int r = i >> 4, c = i & 15;
    s_w1[r*17+c] = mlp_w1[i];
    int r2 = i >> 7, c2 = i & 127;
    s_w2[r2*129+c2] = mlp_w2[i];
  }
  if (t < 48) { s_bih[t] = b_ih[t]; s_bhh[t] = b_hh[t]; }
  if (t < 128) s_b1[t] = mlp_b1[t];
  if (t < 16) {
    s_b2[t] = mlp_b2[t];
    s_lnmw[t] = ln_m_w[t]; s_lnmb[t] = ln_m_b[t];
    s_lnsw[t] = ln_s_w[t]; s_lnsb[t] = ln_s_b[t];
  }
  for (int i = t; i < 256; i += 256) {
    int r = i >> 4, c = i & 15;
    s_wq[r*17+c] = wq[i];
  }
  if (t < 128) {
    qs[t]     = qbuf[b*128 + t];
    sslots[t] = init_slots[b*128 + t];
  }
  __syncthreads();

  const short8 z8 = {0,0,0,0,0,0,0,0};
  #pragma unroll 1
  for (int it = 0; it < 3; ++it) {
    float* upd_it = updp + (size_t)(it*32 + b)*2048;   // [nc][kk][s] slices
    float* As_it  = Asum + (size_t)(it*32 + b)*128;    // [nc][kk]

    // ---- logits + softmax over slots (per n-row = per thread) ----
    float p8[8];
    {
      float lg[8];
      #pragma unroll
      for (int kk = 0; kk < 8; ++kk) {
        float a = 0.f;
        #pragma unroll
        for (int s = 0; s < 16; ++s) a = fmaf(qs[kk*16+s], kv[s], a);
        lg[kk] = a*0.25f;   // scale = 16^-0.5
      }
      float mx = lg[0];
      #pragma unroll
      for (int kk = 1; kk < 8; ++kk) mx = fmaxf(mx, lg[kk]);
      float se = 0.f;
      #pragma unroll
      for (int kk = 0; kk < 8; ++kk) { lg[kk] = __expf(lg[kk]-mx); se += lg[kk]; }
      float inv = 1.f/se;
      #pragma unroll
      for (int kk = 0; kk < 8; ++kk) p8[kk] = fmaf(lg[kk], inv, 1e-8f);
    }
    #pragma unroll
    for (int kk = 0; kk < 8; ++kk) {
      float r = p8[kk];
      r += __shfl_xor(r, 1);  r += __shfl_xor(r, 2);  r += __shfl_xor(r, 4);
      r += __shfl_xor(r, 8);  r += __shfl_xor(r, 16); r += __shfl_xor(r, 32);
      if (lane == 0) apart[w*8 + kk] = r;
    }
    #pragma unroll
    for (int kk = 0; kk < 8; ++kk) {
      short h_, l_;
      split_bf(p8[kk], h_, l_);
      pt[kk*264 + t]     = (ushort_t)h_;
      pt[(8+kk)*264 + t] = (ushort_t)l_;
    }
    __syncthreads();
    // per-block PARTIALS via agent-scope stores (no RMW contention)
    if (t < 8)
      st_agent(As_it + nc*8 + t,
               apart[t] + apart[8+t] + apart[16+t] + apart[24+t]);
    if (w == 0) {   // wave 0: partial updates = P . V via MFMA
      int mm = lane & 15, q2 = lane >> 4;
      f32x4 acc = {0.f,0.f,0.f,0.f};
      #pragma unroll
      for (int c = 0; c < 8; ++c) {
        int k0 = c*32 + q2*8;
        short8 ah = (mm < 8) ? *(const short8*)&pt[mm*264 + k0]     : z8;
        short8 al = (mm < 8) ? *(const short8*)&pt[(8+mm)*264 + k0] : z8;
        short8 bh = *(const short8*)&vt[mm*264 + k0];
        short8 bl = *(const short8*)&vt[(16+mm)*264 + k0];
        acc = __builtin_amdgcn_mfma_f32_16x16x32_bf16(ah, bh, acc, 0, 0, 0);
        acc = __builtin_amdgcn_mfma_f32_16x16x32_bf16(al, bh, acc, 0, 0, 0);
        acc = __builtin_amdgcn_mfma_f32_16x16x32_bf16(ah, bl, acc, 0, 0, 0);
      }
      int s = lane & 15;
      #pragma unroll
      for (int r = 0; r < 4; ++r) {
        int kk = q2*4 + r;
        if (kk < 8) st_agent(upd_it + nc*128 + kk*16 + s, acc[r]);
      }
    }

    // ---- per-(it,b) 16-block barrier: 128B-padded counter, bounded spin ---
    __syncthreads();
    if (t == 0) {
      unsigned* bp = barp + (it*32 + b)*32;   // 128 B apart, zeroed by k_prep
      asm volatile("s_waitcnt vmcnt(0)" ::: "memory");
      atomicAdd(bp, 1u);
      #pragma unroll 1
      for (int spin = 0; spin < (1<<16); ++spin) {   // bounded (~14ms max)
        if (ld_cohpt(bp) >= 16u) break;
        __builtin_amdgcn_s_sleep(8);
      }
    }
    __syncthreads();

    // ---- deterministic reduction of the 16 partial slices ----
    if (t < 8) {
      float a = 0.f;
      #pragma unroll
      for (int nc2 = 0; nc2 < 16; ++nc2) a += ld_agent(As_it + nc2*8 + t);
      apart[t] = a;
    }
    if (t < 128) {
      int bk8 = t >> 4, s = t & 15;
      float us = 0.f;
      #pragma unroll
      for (int nc2 = 0; nc2 < 16; ++nc2)
        us += ld_agent(upd_it + nc2*128 + bk8*16 + s);
      ulds[t] = us;
    }
    __syncthreads();

    // ---- attn write (last it) + redundant per-b GRU ----
    if (it == 2) {
      #pragma unroll
      for (int kk = 0; kk < 8; ++kk)
        attn_out[((size_t)(b*8 + kk))*4096 + n0 + t] = p8[kk]*(1.f/apart[kk]);
    }
    if (t < 128 && (it < 2 || nc == 0)) {
      int bk8 = t >> 4, s = t & 15;
      int laneBase = (t & 63) & ~15;
      float invA = 1.f / apart[bk8];
      float u[16], h[16];
      #pragma unroll
      for (int j = 0; j < 16; ++j) {
        u[j] = ulds[bk8*16 + j] * invA;
        h[j] = sslots[bk8*16 + j];
      }
      float hs = h[s];
      float gir = s_bih[s],  giz = s_bih[16+s], gin = s_bih[32+s];
      float ghr = s_bhh[s],  ghz = s_bhh[16+s], ghn = s_bhh[32+s];
      #pragma unroll
      for (int j = 0; j < 16; ++j) {
        gir = fmaf(u[j], s_wih[s*17+j], gir);
        giz = fmaf(u[j], s_wih[(16+s)*17+j], giz);
        gin = fmaf(u[j], s_wih[(32+s)*17+j], gin);
        ghr = fmaf(h[j], s_whh[s*17+j], ghr);
        ghz = fmaf(h[j], s_whh[(16+s)*17+j], ghz);
        ghn = fmaf(h[j], s_whh[(32+s)*17+j], ghn);
      }
      float rr_ = sigmoid_f(gir + ghr);
      float zz = sigmoid_f(giz + ghz);
      float nn = tanh_f(gin + rr_*ghn);
      float hn = (1.f - zz)*nn + zz*hs;

      float ssum = hn;
      #pragma unroll
      for (int mm = 1; mm < 16; mm <<= 1) ssum += __shfl_xor(ssum, mm);
      float mu = ssum*(1.f/16.f);
      float dv = hn - mu;
      float vs = dv*dv;
      #pragma unroll
      for (int mm = 1; mm < 16; mm <<= 1) vs += __shfl_xor(vs, mm);
      float rstd = rsqrtf(vs*(1.f/16.f) + 1e-5f);
      float y = dv*rstd*s_lnmw[s] + s_lnmb[s];

      float yv[16];
      #pragma unroll
      for (int j = 0; j < 16; ++j) yv[j] = __shfl(y, laneBase + j);

      float h1[8];
      #pragma unroll
      for (int i = 0; i < 8; ++i) {
        int jj = i*16 + s;
        float a = s_b1[jj];
        #pragma unroll
        for (int q = 0; q < 16; ++q) a = fmaf(yv[q], s_w1[jj*17+q], a);
        h1[i] = fmaxf(a, 0.f);
      }
      float o = s_b2[s];
      #pragma unroll
      for (int i = 0; i < 8; ++i) {
        #pragma unroll
        for (int sp = 0; sp < 16; ++sp) {
          float hv = __shfl(h1[i], laneBase + sp);
          o = fmaf(hv, s_w2[s*129 + i*16 + sp], o);
        }
      }
      float slot_new = hn + o;
      if (it < 2) {
        sslots[bk8*16 + s] = slot_new;
        float ss = slot_new;
        #pragma unroll
        for (int mm = 1; mm < 16; mm <<= 1) ss += __shfl_xor(ss, mm);
        float mu2 = ss*(1.f/16.f);
        float d2 = slot_new - mu2;
        float v2 = d2*d2;
        #pragma unroll
        for (int mm = 1; mm < 16; mm <<= 1) v2 += __shfl_xor(v2, mm);
        float rstd2 = rsqrtf(v2*(1.f/16.f) + 1e-5f);
        float y2 = d2*rstd2*s_lnsw[s] + s_lnsb[s];
        float qv = 0.f;
        #pragma unroll
        for (int sp = 0; sp < 16; ++sp)
          qv = fmaf(__shfl(y2, laneBase + sp), s_wq[s*17+sp], qv);
        qs[bk8*16 + s] = qv;
      } else {
        slots_out[(b*8 + bk8)*16 + s] = slot_new;
      }
    }
    __syncthreads();
  }
}

// ======================= LEGACY FALLBACK ITERATION PATH ====================

__global__ __launch_bounds__(256) void k_attn(
    const float* __restrict__ kproj, const float* __restrict__ vproj,
    const float* __restrict__ qbuf,
    float* __restrict__ upd, float* __restrict__ Abuf,
    float* __restrict__ attn_out, int write_attn)
{
  __shared__ ushort_t vt[32*264];
  __shared__ ushort_t pt[32*264];
  __shared__ float qs[128];
  __shared__ float apart[4][8];
  int b = blockIdx.x >> 4;
  int n0 = (blockIdx.x & 15) * 256;
  int t = threadIdx.x;
  int w = t >> 6, lane = t & 63;

  if (t < 128) qs[t] = qbuf[b*128 + t];

  const float* kr = kproj + ((size_t)(b*4096 + n0 + t))*16;
  const float* vr = vproj + ((size_t)(b*4096 + n0 + t))*16;
  float kv[16], vv[16];
  #pragma unroll
  for (int j = 0; j < 16; j += 4) {
    float4 f = *(const float4*)(kr+j);
    kv[j]=f.x; kv[j+1]=f.y; kv[j+2]=f.z; kv[j+3]=f.w;
    float4 g = *(const float4*)(vr+j);
    vv[j]=g.x; vv[j+1]=g.y; vv[j+2]=g.z; vv[j+3]=g.w;
  }
  #pragma unroll
  for (int s = 0; s < 16; ++s) {
    short h_, l_;
    split_bf(vv[s], h_, l_);
    vt[s*264 + t] = (ushort_t)h_;
    vt[(16+s)*264 + t] = (ushort_t)l_;
  }
  __syncthreads();

  float p8[8];
  {
    float lg[8];
    #pragma unroll
    for (int kk = 0; kk < 8; ++kk) {
      float a = 0.f;
      #pragma unroll
      for (int s = 0; s < 16; ++s) a = fmaf(qs[kk*16+s], kv[s], a);
      lg[kk] = a*0.25f;
    }
    float mx = lg[0];
    #pragma unroll
    for (int kk = 1; kk < 8; ++kk) mx = fmaxf(mx, lg[kk]);
    float se = 0.f;
    #pragma unroll
    for (int kk = 0; kk < 8; ++kk) { lg[kk] = __expf(lg[kk]-mx); se += lg[kk]; }
    float inv = 1.f/se;
    #pragma unroll
    for (int kk = 0; kk < 8; ++kk) {
      float pv = fmaf(lg[kk], inv, 1e-8f);
      p8[kk] = pv;
      if (write_attn) attn_out[((size_t)(b*8+kk))*4096 + n0 + t] = pv;
    }
  }
  #pragma unroll
  for (int kk = 0; kk < 8; ++kk) {
    float r = p8[kk];
    r += __shfl_xor(r, 1);  r += __shfl_xor(r, 2);  r += __shfl_xor(r, 4);
    r += __shfl_xor(r, 8);  r += __shfl_xor(r, 16); r += __shfl_xor(r, 32);
    if (lane == 0) apart[w][kk] = r;
  }
  #pragma unroll
  for (int kk = 0; kk < 8; ++kk) {
    short h_, l_;
    split_bf(p8[kk], h_, l_);
    pt[kk*264 + t] = (ushort_t)h_;
    pt[(16+kk)*264 + t] = (ushort_t)l_;
  }
  __syncthreads();

  if (t < 8)
    atomicAdd(Abuf + b*8 + t,
              apart[0][t] + apart[1][t] + apart[2][t] + apart[3][t]);

  if (w == 0) {
    int mm = lane & 15, quad = lane >> 4;
    const short8 z8 = {0,0,0,0,0,0,0,0};
    f32x4 acc = {0.f,0.f,0.f,0.f};
    #pragma unroll
    for (int c = 0; c < 8; ++c) {
      int k0 = c*32 + quad*8;
      short8 ah = (mm < 8) ? *(const short8*)&pt[mm*264 + k0]      : z8;
      short8 al = (mm < 8) ? *(const short8*)&pt[(16+mm)*264 + k0] : z8;
      short8 bh = *(const short8*)&vt[mm*264 + k0];
      short8 bl = *(const short8*)&vt[(16+mm)*264 + k0];
      acc = __builtin_amdgcn_mfma_f32_16x16x32_bf16(ah, bh, acc, 0, 0, 0);
      acc = __builtin_amdgcn_mfma_f32_16x16x32_bf16(al, bh, acc, 0, 0, 0);
      acc = __builtin_amdgcn_mfma_f32_16x16x32_bf16(ah, bl, acc, 0, 0, 0);
    }
    int s = lane & 15;
    #pragma unroll
    for (int r = 0; r < 4; ++r) {
      int kk = quad*4 + r;
      if (kk < 8) atomicAdd(upd + (b*8+kk)*16 + s, acc[r]);
    }
  }
}

__device__ __forceinline__ void gru_body(
    int bk, int s, int laneBase, int prep_next,
    float* upd, float* Abuf, float* slots, float* qbuf,
    const float* s_wih, const float* s_whh,
    const float* s_bih, const float* s_bhh,
    const float* s_w1, const float* s_b1,
    const float* s_w2, const float* s_b2,
    const float* s_lnmw, const float* s_lnmb,
    const float* s_lnsw, const float* s_lnsb, const float* s_wq)
{
  float inv = 1.f / Abuf[bk];
  float u[16], h[16];
  #pragma unroll
  for (int j = 0; j < 16; ++j) {
    u[j] = upd[bk*16+j] * inv;
    h[j] = slots[bk*16+j];
  }
  float hs = slots[bk*16+s];

  float gir = s_bih[s],  giz = s_bih[16+s], gin = s_bih[32+s];
  float ghr = s_bhh[s],  ghz = s_bhh[16+s], ghn = s_bhh[32+s];
  #pragma unroll
  for (int j = 0; j < 16; ++j) {
    gir = fmaf(u[j], s_wih[s*17+j], gir);
    giz = fmaf(u[j], s_wih[(16+s)*17+j], giz);
    gin = fmaf(u[j], s_wih[(32+s)*17+j], gin);
    ghr = fmaf(h[j], s_whh[s*17+j], ghr);
    ghz = fmaf(h[j], s_whh[(16+s)*17+j], ghz);
    ghn = fmaf(h[j], s_whh[(32+s)*17+j], ghn);
  }
  float rr = sigmoid_f(gir + ghr);
  float zz = sigmoid_f(giz + ghz);
  float nn = tanh_f(gin + rr*ghn);
  float hn = (1.f-zz)*nn + zz*hs;

  float ssum = hn;
  #pragma unroll
  for (int mm = 1; mm < 16; mm <<= 1) ssum += __shfl_xor(ssum, mm);
  float mu = ssum*(1.f/16.f);
  float dv = hn - mu;
  float vs = dv*dv;
  #pragma unroll
  for (int mm = 1; mm < 16; mm <<= 1) vs += __shfl_xor(vs, mm);
  float rstd = rsqrtf(vs*(1.f/16.f) + 1e-5f);
  float y = dv*rstd*s_lnmw[s] + s_lnmb[s];

  float yv[16];
  #pragma unroll
  for (int j = 0; j < 16; ++j) yv[j] = __shfl(y, laneBase + j);

  float h1[8];
  #pragma unroll
  for (int i = 0; i < 8; ++i) {
    int jj = i*16 + s;
    float a = s_b1[jj];
    #pragma unroll
    for (int q = 0; q < 16; ++q) a = fmaf(yv[q], s_w1[jj*17+q], a);
    h1[i] = fmaxf(a, 0.f);
  }
  float o = s_b2[s];
  #pragma unroll
  for (int i = 0; i < 8; ++i) {
    #pragma unroll
    for (int sp = 0; sp < 16; ++sp) {
      float hv = __shfl(h1[i], laneBase + sp);
      o = fmaf(hv, s_w2[s*129 + i*16 + sp], o);
    }
  }
  float slot_new = hn + o;
  slots[bk*16+s] = slot_new;

  if (prep_next) {
    float ss = slot_new;
    #pragma unroll
    for (int mm = 1; mm < 16; mm <<= 1) ss += __shfl_xor(ss, mm);
    float mu2 = ss*(1.f/16.f);
    float d2 = slot_new - mu2;
    float v2 = d2*d2;
    #pragma unroll
    for (int mm = 1; mm < 16; mm <<= 1) v2 += __shfl_xor(v2, mm);
    float rstd2 = rsqrtf(v2*(1.f/16.f) + 1e-5f);
    float y2 = d2*rstd2*s_lnsw[s] + s_lnsb[s];
    float qv = 0.f;
    #pragma unroll
    for (int sp = 0; sp < 16; ++sp)
      qv = fmaf(__shfl(y2, laneBase+sp), s_wq[s*17+sp], qv);
    qbuf[bk*16+s] = qv;
    upd[bk*16+s] = 0.f;
    if (s == 0) Abuf[bk] = 0.f;
  }
}

#define GRU_STAGE_LDS()                                                      \
  __shared__ float s_wih[48*17], s_whh[48*17];                               \
  __shared__ float s_bih[48], s_bhh[48];                                     \
  __shared__ float s_w1[128*17], s_b1[128];                                  \
  __shared__ float s_w2[16*129], s_b2[16];                                   \
  __shared__ float s_lnmw[16], s_lnmb[16], s_lnsw[16], s_lnsb[16];           \
  __shared__ float s_wq[16*17];                                              \
  {                                                                          \
    int t_ = threadIdx.x;                                                    \
    for (int i = t_; i < 768; i += 256) {                                    \
      int g = i >> 4, j = i & 15;                                            \
      s_wih[g*17+j] = w_ih[i];                                               \
      s_whh[g*17+j] = w_hh[i];                                               \
    }                                                                        \
    for (int i = t_; i < 2048; i += 256) {                                   \
      int r = i >> 4, c = i & 15;                                            \
      s_w1[r*17+c] = mlp_w1[i];                                              \
      int r2 = i >> 7, c2 = i & 127;                                         \
      s_w2[r2*129+c2] = mlp_w2[i];                                           \
    }                                                                        \
    if (t_ < 48) { s_bih[t_] = b_ih[t_]; s_bhh[t_] = b_hh[t_]; }             \
    if (t_ < 128) s_b1[t_] = mlp_b1[t_];                                     \
    if (t_ < 16) {                                                           \
      s_b2[t_] = mlp_b2[t_];                                                 \
      s_lnmw[t_] = ln_m_w[t_]; s_lnmb[t_] = ln_m_b[t_];                      \
      s_lnsw[t_] = ln_s_w[t_]; s_lnsb[t_] = ln_s_b[t_];                      \
    }                                                                        \
    for (int i = t_; i < 256; i += 256) {                                    \
      int r = i >> 4, c = i & 15;                                            \
      s_wq[r*17+c] = wq[i];                                                  \
    }                                                                        \
  }                                                                          \
  __syncthreads();

__global__ __launch_bounds__(256) void k_gru(
    float* __restrict__ upd, float* __restrict__ Abuf,
    float* __restrict__ slots, float* __restrict__ qbuf,
    const float* __restrict__ w_ih, const float* __restrict__ w_hh,
    const float* __restrict__ b_ih, const float* __restrict__ b_hh,
    const float* __restrict__ mlp_w1, const float* __restrict__ mlp_b1,
    const float* __restrict__ mlp_w2, const float* __restrict__ mlp_b2,
    const float* __restrict__ ln_m_w, const float* __restrict__ ln_m_b,
    const float* __restrict__ ln_s_w, const float* __restrict__ ln_s_b,
    const float* __restrict__ wq)
{
  GRU_STAGE_LDS()
  int t = threadIdx.x;
  int bk = blockIdx.x*16 + (t >> 4);
  int s = t & 15;
  int laneBase = (t & 63) & ~15;
  gru_body(bk, s, laneBase, 1, upd, Abuf, slots, qbuf,
           s_wih, s_whh, s_bih, s_bhh, s_w1, s_b1, s_w2, s_b2,
           s_lnmw, s_lnmb, s_lnsw, s_lnsb, s_wq);
}

__global__ __launch_bounds__(256) void k_final(
    float* __restrict__ upd, float* __restrict__ Abuf,
    float* __restrict__ slots, float* __restrict__ qbuf,
    float* __restrict__ attn,
    const float* __restrict__ w_ih, const float* __restrict__ w_hh,
    const float* __restrict__ b_ih, const float* __restrict__ b_hh,
    const float* __restrict__ mlp_w1, const float* __restrict__ mlp_b1,
    const float* __restrict__ mlp_w2, const float* __restrict__ mlp_b2,
    const float* __restrict__ ln_m_w, const float* __restrict__ ln_m_b,
    const float* __restrict__ ln_s_w, const float* __restrict__ ln_s_b,
    const float* __restrict__ wq)
{
  int t = threadIdx.x;
  {
    int bk = blockIdx.x;
    float inv = 1.f / Abuf[bk];
    float4* p = (float4*)(attn + (size_t)bk*4096);
    #pragma unroll 4
    for (int i = t; i < 1024; i += 256) {
      float4 v = p[i];
      v.x *= inv; v.y *= inv; v.z *= inv; v.w *= inv;
      p[i] = v;
    }
  }
  if (blockIdx.x >= 16) return;
  GRU_STAGE_LDS()
  int bk = blockIdx.x*16 + (t >> 4);
  int s = t & 15;
  int laneBase = (t & 63) & ~15;
  gru_body(bk, s, laneBase, 0, upd, Abuf, slots, qbuf,
           s_wih, s_whh, s_bih, s_bhh, s_w1, s_b1, s_w2, s_b2,
           s_lnmw, s_lnmb, s_lnsw, s_lnsb, s_wq);
}

extern "C" void kernel_launch(void* const* d_in, const int* in_sizes, int n_in,
                              void* d_out, int out_size, void* d_ws, size_t ws_size,
                              hipStream_t stream)
{
  const float* inputs     = (const float*)d_in[0];
  const float* init_slots = (const float*)d_in[1];
  const float* ln_in_w    = (const float*)d_in[2];
  const float* ln_in_b    = (const float*)d_in[3];
  const float* ln_s_w     = (const float*)d_in[4];
  const float* ln_s_b     = (const float*)d_in[5];
  const float* ln_m_w     = (const float*)d_in[6];
  const float* ln_m_b     = (const float*)d_in[7];
  const float* wq         = (const float*)d_in[8];
  const float* wk         = (const float*)d_in[9];
  const float* wv         = (const float*)d_in[10];
  const float* w_ih       = (const float*)d_in[11];
  const float* w_hh       = (const float*)d_in[12];
  const float* b_ih       = (const float*)d_in[13];
  const float* b_hh       = (const float*)d_in[14];
  const float* mlp_w1     = (const float*)d_in[15];
  const float* mlp_b1     = (const float*)d_in[16];
  const float* mlp_w2     = (const float*)d_in[17];
  const float* mlp_b2     = (const float*)d_in[18];

  float* ws = (float*)d_ws;
  // k_iter workspace
  unsigned* barp = (unsigned*)ws;        // 3*32 counters x 32 uints = 12 KB
  float* updp = ws + 3072;               // 3*32*16*128 = 196608 floats
  float* Asum = ws + 3072 + 196608;      // 3*32*16*8  = 12288 floats
  // shared/legacy workspace
  float* lg    = ws + 211968;
  ushort_t* Wh = (ushort_t*)lg;          // 8192 ushorts
  ushort_t* Wl = (ushort_t*)(lg + 4096);
  float* mt    = lg + 8192;              // 64
  float* qbuf  = lg + 8320;              // 4096
  float* upd   = lg + 12416;             // 4096 (legacy)
  float* Abuf  = lg + 16512;             // 256  (legacy)
  float* kproj = lg + 16768;             // 2097152
  float* vproj = kproj + 2097152;        // 2097152

  float* out   = (float*)d_out;
  float* slots = out;                // [32,8,16]
  float* attn  = out + 4096;         // [32,8,4096]

  // Launch-mode decision (R2/R4/R5-validated pattern, applied to k_iter):
  // plain launch only if the occupancy query certifies 512 co-resident
  // blocks; else cooperative; else legacy iteration pipeline.
  static int s_mode = -1;
  if (s_mode < 0) {
    int dev = 0;
    (void)hipGetDevice(&dev);
    int ncu = 0;
    (void)hipDeviceGetAttribute(&ncu, hipDeviceAttributeMultiprocessorCount, dev);
    int nb = 0;
    if (hipOccupancyMaxActiveBlocksPerMultiprocessor(&nb, (const void*)k_iter,
                                                     256, 0) != hipSuccess)
      nb = 0;
    s_mode = (nb > 0 && ncu > 0 && (long)nb * ncu >= 512) ? 0 : 1;
  }

  k_prep<<<32, 256, 0, stream>>>(ln_in_w, ln_in_b, wk, wv, init_slots,
                                 ln_s_w, ln_s_b, wq,
                                 Wh, Wl, mt, qbuf, upd, Abuf, barp, slots);
  k_proj<<<2048, 256, 0, stream>>>(inputs, Wh, Wl, mt, kproj, vproj);

  if (s_mode == 0) {
    k_iter<<<512, 256, 0, stream>>>(kproj, vproj, qbuf, init_slots,
                                    updp, Asum, barp, slots, attn,
                                    w_ih, w_hh, b_ih, b_hh,
                                    mlp_w1, mlp_b1, mlp_w2, mlp_b2,
                                    ln_m_w, ln_m_b, ln_s_w, ln_s_b, wq);
    return;
  }

  // ---- cooperative fallback (residency-guaranteed launch, same kernel) ----
  {
    void* kargs[] = {
      (void*)&kproj, (void*)&vproj, (void*)&qbuf, (void*)&init_slots,
      (void*)&updp, (void*)&Asum, (void*)&barp, (void*)&slots, (void*)&attn,
      (void*)&w_ih, (void*)&w_hh, (void*)&b_ih, (void*)&b_hh,
      (void*)&mlp_w1, (void*)&mlp_b1, (void*)&mlp_w2, (void*)&mlp_b2,
      (void*)&ln_m_w, (void*)&ln_m_b, (void*)&ln_s_w, (void*)&ln_s_b,
      (void*)&wq };
    hipError_t err = hipLaunchCooperativeKernel((const void*)k_iter,
                                                dim3(512), dim3(256),
                                                kargs, 0, stream);
    if (err == hipSuccess) return;
    (void)hipGetLastError();   // clear error, fall back to legacy pipeline
  }

  // ---- legacy fallback (verified multi-kernel iteration pipeline) ----
  for (int it = 0; it < 3; ++it) {
    int last = (it == 2);
    k_attn<<<512, 256, 0, stream>>>(kproj, vproj, qbuf, upd, Abuf, attn, last);
    if (!last)
      k_gru<<<16, 256, 0, stream>>>(upd, Abuf, slots, qbuf,
                                    w_ih, w_hh, b_ih, b_hh,
                                    mlp_w1, mlp_b1, mlp_w2, mlp_b2,
                                    ln_m_w, ln_m_b, ln_s_w, ln_s_b, wq);
  }
  k_final<<<256, 256, 0, stream>>>(upd, Abuf, slots, qbuf, attn,
                                   w_ih, w_hh, b_ih, b_hh,
                                   mlp_w1, mlp_b1, mlp_w2, mlp_b2,
                                   ln_m_w, ln_m_b, ln_s_w, ln_s_b, wq);
}

// Round 8
// 290.617 us; speedup vs baseline: 1.1175x; 1.1175x over previous
//
#include <hip/hip_runtime.h>
#include <cstddef>

// Problem constants: B=32, N=4096, D=256, K=8 slots, S=16, H=128, 3 iters.
// Strategy (R7 post-mortem): wall = ~205us fixed harness overhead + SUM of
// kernel times; kernel-boundary sync is ~free, in-kernel barriers cost
// ~12-15us/iteration (measured 3 ways, R1-R7). So: legacy 8-dispatch
// pipeline, each kernel individually optimized. This round: V is written
// pre-split (bf16 hi/lo) and TRANSPOSED by k_proj, so k_attn needs no V
// load, no split math, no V LDS staging.

typedef unsigned short ushort_t;
typedef __attribute__((ext_vector_type(8))) short short8;   // 8 bf16 = 4 VGPRs
typedef __attribute__((ext_vector_type(4))) float f32x4;

#define VT_PLANE 2097152   // 32*16*4096 ushorts per plane (hi plane, lo plane)

__device__ __forceinline__ float sigmoid_f(float x){ return 1.f/(1.f+__expf(-x)); }
__device__ __forceinline__ float tanh_f(float x){ return 1.f - 2.f/(__expf(2.f*x)+1.f); }

// fp32 -> bf16 (RNE), as raw bits (weights + mt consistency)
__device__ __forceinline__ ushort_t f2bf(float x){
  unsigned u = __float_as_uint(x);
  return (ushort_t)((u + 0x7FFFu + ((u>>16)&1u)) >> 16);
}
__device__ __forceinline__ float bf2f(ushort_t b){
  return __uint_as_float(((unsigned)b) << 16);
}
// truncation hi/lo split (cheap: AND/SUB/SHR), combined rel err ~2^-17
__device__ __forceinline__ void split_bf(float v, short& hi, short& lo){
  unsigned u = __float_as_uint(v);
  hi = (short)(u >> 16);
  float hf = __uint_as_float(u & 0xFFFF0000u);
  lo = (short)(__float_as_uint(v - hf) >> 16);
}

// ---------------- K0: prep (bf16-split weights, init slots, q1, zeros) -----
__global__ __launch_bounds__(256) void k_prep(
    const float* __restrict__ lnw, const float* __restrict__ lnb,
    const float* __restrict__ wk, const float* __restrict__ wv,
    const float* __restrict__ init_slots,
    const float* __restrict__ ln_s_w, const float* __restrict__ ln_s_b,
    const float* __restrict__ wq,
    ushort_t* __restrict__ Wh, ushort_t* __restrict__ Wl,
    float* __restrict__ mt,
    float* __restrict__ qbuf, float* __restrict__ upd, float* __restrict__ Abuf,
    float* __restrict__ slots_out)
{
  int t = threadIdx.x;
  int i = blockIdx.x*256 + t;          // 32*256 == 8192 exactly
  {
    int s = i >> 8, d = i & 255;
    float w = (s < 16) ? wk[s*256+d] : wv[(s-16)*256+d];
    float w0 = lnw[d]*w;
    ushort_t hb = f2bf(w0);
    ushort_t lb = f2bf(w0 - bf2f(hb));
    Wh[i] = hb; Wl[i] = lb;
  }
  if (blockIdx.x != 0) return;
  // m[s] from QUANTIZED weights; t[s] exact fp32
  {
    int s = t >> 3, j = t & 7;
    float m = 0.f, tv = 0.f;
    for (int d = j; d < 256; d += 8) {
      float w = (s < 16) ? wk[s*256+d] : wv[(s-16)*256+d];
      float w0 = lnw[d]*w;
      ushort_t hb = f2bf(w0);
      float hf = bf2f(hb);
      float lf = bf2f(f2bf(w0 - hf));
      m  += hf + lf;
      tv  = fmaf(lnb[d], w, tv);
    }
    m += __shfl_xor(m,1);  m += __shfl_xor(m,2);  m += __shfl_xor(m,4);
    tv += __shfl_xor(tv,1); tv += __shfl_xor(tv,2); tv += __shfl_xor(tv,4);
    if (j == 0) { mt[s] = m; mt[32+s] = tv; }
  }
  #pragma unroll
  for (int j2 = 0; j2 < 16; ++j2) {
    slots_out[t*16+j2] = init_slots[t*16+j2];
    upd[t*16+j2] = 0.f;
  }
  Abuf[t] = 0.f;
  // q for iteration 1: thread t = (b,k) row
  float sl[16];
  #pragma unroll
  for (int j2 = 0; j2 < 16; ++j2) sl[j2] = init_slots[t*16+j2];
  float mu = 0.f;
  #pragma unroll
  for (int j2 = 0; j2 < 16; ++j2) mu += sl[j2];
  mu *= (1.f/16.f);
  float var = 0.f;
  #pragma unroll
  for (int j2 = 0; j2 < 16; ++j2) { float d = sl[j2]-mu; var = fmaf(d,d,var); }
  var *= (1.f/16.f);
  float rstd = rsqrtf(var + 1e-5f);
  float y[16];
  #pragma unroll
  for (int j2 = 0; j2 < 16; ++j2) y[j2] = (sl[j2]-mu)*rstd*ln_s_w[j2] + ln_s_b[j2];
  #pragma unroll
  for (int tq = 0; tq < 16; ++tq) {
    float q = 0.f;
    #pragma unroll
    for (int s2 = 0; s2 < 16; ++s2) q = fmaf(y[s2], wq[tq*16+s2], q);
    qbuf[t*16+tq] = q;
  }
}

// ---------------- K1: fused LayerNorm + K/V projection ---------------------
// Proven 2048-block / 4-per-CU shape. NEW: v is written as TRANSPOSED
// bf16 hi/lo planes vT[plane][(b*16+s)*4096+n] (via 4KB LDS bounce), so
// k_attn consumes V fragments directly from global with zero staging.
// k stays fp32 n-major (per-thread row reads in k_attn).
__global__ __launch_bounds__(256, 4) void k_proj(
    const float* __restrict__ x, const ushort_t* __restrict__ Wh,
    const ushort_t* __restrict__ Wl, const float* __restrict__ mt,
    float* __restrict__ kout, ushort_t* __restrict__ vT)
{
  __shared__ ushort_t wlds[64*264];   // 33 KB
  __shared__ ushort_t vtile[2*1024];  // 4 KB: [plane][s*64 + lrow]
  int t = threadIdx.x;
  int lane = t & 63;
  int p = __builtin_amdgcn_readfirstlane(t >> 6);
  int m = lane & 15, quad = lane >> 4;
  int r0 = blockIdx.x*64;
  {
    const unsigned* srcH = (const unsigned*)Wh;
    const unsigned* srcL = (const unsigned*)Wl;
    unsigned* dst = (unsigned*)wlds;
    #pragma unroll
    for (int i0 = 0; i0 < 8192; i0 += 256) {
      int i = i0 + t;
      int r = i >> 7, w = i & 127;
      unsigned v = (r < 32) ? srcH[r*128 + w] : srcL[(r-32)*128 + w];
      dst[r*132 + w] = v;
    }
  }
  __syncthreads();

  const ushort_t* rhk = wlds + (size_t)m*264 + quad*8;
  const ushort_t* rhv = wlds + (size_t)(16+m)*264 + quad*8;
  const ushort_t* rlk = wlds + (size_t)(32+m)*264 + quad*8;
  const ushort_t* rlv = wlds + (size_t)(48+m)*264 + quad*8;

  const float* xr = x + (size_t)(r0 + p*16 + m)*256 + quad*8;

  f32x4 acck = {0.f,0.f,0.f,0.f}, accv = {0.f,0.f,0.f,0.f};
  float sum = 0.f, sumsq = 0.f;

  #pragma unroll
  for (int kk = 0; kk < 8; ++kk) {
    float4 a0 = *(const float4*)(xr + kk*32);
    float4 a1 = *(const float4*)(xr + kk*32 + 4);
    short8 bh_k = *(const short8*)(rhk + kk*32);
    short8 bh_v = *(const short8*)(rhv + kk*32);
    short8 bl_k = *(const short8*)(rlk + kk*32);
    short8 bl_v = *(const short8*)(rlv + kk*32);
    float xv[8] = {a0.x,a0.y,a0.z,a0.w, a1.x,a1.y,a1.z,a1.w};
    short8 ah, al;
    #pragma unroll
    for (int j = 0; j < 8; ++j) {
      float v = xv[j];
      sum += v; sumsq = fmaf(v, v, sumsq);
      short h_, l_;
      split_bf(v, h_, l_);
      ah[j] = h_; al[j] = l_;
    }
    acck = __builtin_amdgcn_mfma_f32_16x16x32_bf16(ah, bh_k, acck, 0, 0, 0);
    accv = __builtin_amdgcn_mfma_f32_16x16x32_bf16(ah, bh_v, accv, 0, 0, 0);
    acck = __builtin_amdgcn_mfma_f32_16x16x32_bf16(al, bh_k, acck, 0, 0, 0);
    accv = __builtin_amdgcn_mfma_f32_16x16x32_bf16(al, bh_v, accv, 0, 0, 0);
    acck = __builtin_amdgcn_mfma_f32_16x16x32_bf16(ah, bl_k, acck, 0, 0, 0);
    accv = __builtin_amdgcn_mfma_f32_16x16x32_bf16(ah, bl_v, accv, 0, 0, 0);
  }

  sum   += __shfl_xor(sum, 16);  sum   += __shfl_xor(sum, 32);
  sumsq += __shfl_xor(sumsq, 16); sumsq += __shfl_xor(sumsq, 32);

  float mtk  = mt[m],    mtv  = mt[16+m];
  float mtkb = mt[32+m], mtvb = mt[48+m];
  #pragma unroll
  for (int r = 0; r < 4; ++r) {
    int row = quad*4 + r;                  // C row within the wave tile
    float s_ = __shfl(sum,   row);
    float q_ = __shfl(sumsq, row);
    float mu = s_*(1.f/256.f);
    float var = q_*(1.f/256.f) - mu*mu;
    float rstd = rsqrtf(var + 1e-5f);
    float ok = fmaf(rstd, acck[r] - mu*mtk, mtkb);
    float ov = fmaf(rstd, accv[r] - mu*mtv, mtvb);
    int lrow = p*16 + row;                 // 0..63 within block
    kout[(size_t)(r0 + lrow)*16 + m] = ok;
    short h_, l_;
    split_bf(ov, h_, l_);                  // same fp32 value as before ->
    vtile[m*64 + lrow]        = (ushort_t)h_;   // bit-identical numerics
    vtile[1024 + m*64 + lrow] = (ushort_t)l_;
  }
  __syncthreads();
  // write vT: 2 planes x 16 s x 64 n ushorts = 4KB; thread t -> 16B
  {
    int plane = t >> 7;        // 0..1
    int idx   = t & 127;       // s = idx>>3, n-seg = (idx&7)*8
    int s = idx >> 3;
    int b = r0 >> 12, nbase = r0 & 4095;
    short8 v8 = *(const short8*)&vtile[plane*1024 + idx*8];
    *(short8*)&vT[(size_t)plane*VT_PLANE + ((size_t)(b*16 + s))*4096
                  + nbase + (idx & 7)*8] = v8;
  }
}

// ---------------- K2: logits + softmax-over-slots + MFMA update ------------
// V path removed entirely: wave0 loads PV B-fragments straight from the
// L3-hot vT planes. LDS = pt(8.4K)+qs+apart ~9KB -> high occupancy.
__global__ __launch_bounds__(256) void k_attn(
    const float* __restrict__ kproj, const ushort_t* __restrict__ vT,
    const float* __restrict__ qbuf,
    float* __restrict__ upd, float* __restrict__ Abuf,
    float* __restrict__ attn_out, int write_attn)
{
  __shared__ ushort_t pt[16*264];   // rows 0..7 = p_hi[kk][n], 8..15 = p_lo
  __shared__ float qs[128];
  __shared__ float apart[4][8];
  int b = blockIdx.x >> 4;
  int n0 = (blockIdx.x & 15) * 256;
  int t = threadIdx.x;
  int w = t >> 6, lane = t & 63;

  if (t < 128) qs[t] = qbuf[b*128 + t];

  const float* kr = kproj + ((size_t)(b*4096 + n0 + t))*16;
  float kv[16];
  #pragma unroll
  for (int j = 0; j < 16; j += 4) {
    float4 f = *(const float4*)(kr+j);
    kv[j]=f.x; kv[j+1]=f.y; kv[j+2]=f.z; kv[j+3]=f.w;
  }
  __syncthreads();   // qs ready

  float p8[8];
  {
    float lg[8];
    #pragma unroll
    for (int kk = 0; kk < 8; ++kk) {
      float a = 0.f;
      #pragma unroll
      for (int s = 0; s < 16; ++s) a = fmaf(qs[kk*16+s], kv[s], a);
      lg[kk] = a*0.25f;  // scale = 16^-0.5
    }
    float mx = lg[0];
    #pragma unroll
    for (int kk = 1; kk < 8; ++kk) mx = fmaxf(mx, lg[kk]);
    float se = 0.f;
    #pragma unroll
    for (int kk = 0; kk < 8; ++kk) { lg[kk] = __expf(lg[kk]-mx); se += lg[kk]; }
    float inv = 1.f/se;
    #pragma unroll
    for (int kk = 0; kk < 8; ++kk) {
      float pv = fmaf(lg[kk], inv, 1e-8f);   // softmax + EPS (pre-renorm)
      p8[kk] = pv;
      if (write_attn) attn_out[((size_t)(b*8+kk))*4096 + n0 + t] = pv;
    }
  }
  #pragma unroll
  for (int kk = 0; kk < 8; ++kk) {
    float r = p8[kk];
    r += __shfl_xor(r, 1);  r += __shfl_xor(r, 2);  r += __shfl_xor(r, 4);
    r += __shfl_xor(r, 8);  r += __shfl_xor(r, 16); r += __shfl_xor(r, 32);
    if (lane == 0) apart[w][kk] = r;
  }
  #pragma unroll
  for (int kk = 0; kk < 8; ++kk) {
    short h_, l_;
    split_bf(p8[kk], h_, l_);
    pt[kk*264 + t]     = (ushort_t)h_;
    pt[(8+kk)*264 + t] = (ushort_t)l_;
  }
  __syncthreads();

  if (t < 8)
    atomicAdd(Abuf + b*8 + t,
              apart[0][t] + apart[1][t] + apart[2][t] + apart[3][t]);

  if (w == 0) {   // wave 0: updates = P . V via MFMA; V fragments from vT
    int mm = lane & 15, quad = lane >> 4;
    const short8 z8 = {0,0,0,0,0,0,0,0};
    const ushort_t* vhi = vT + ((size_t)(b*16 + mm))*4096 + n0;
    const ushort_t* vlo = vhi + (size_t)VT_PLANE;
    f32x4 acc = {0.f,0.f,0.f,0.f};
    #pragma unroll
    for (int c = 0; c < 8; ++c) {
      int k0 = c*32 + quad*8;
      short8 ah = (mm < 8) ? *(const short8*)&pt[mm*264 + k0]     : z8;
      short8 al = (mm < 8) ? *(const short8*)&pt[(8+mm)*264 + k0] : z8;
      short8 bh = *(const short8*)(vhi + k0);
      short8 bl = *(const short8*)(vlo + k0);
      acc = __builtin_amdgcn_mfma_f32_16x16x32_bf16(ah, bh, acc, 0, 0, 0);
      acc = __builtin_amdgcn_mfma_f32_16x16x32_bf16(al, bh, acc, 0, 0, 0);
      acc = __builtin_amdgcn_mfma_f32_16x16x32_bf16(ah, bl, acc, 0, 0, 0);
    }
    int s = lane & 15;
    #pragma unroll
    for (int r = 0; r < 4; ++r) {
      int kk = quad*4 + r;
      if (kk < 8) atomicAdd(upd + (b*8+kk)*16 + s, acc[r]);
    }
  }
}

// -------- GRU cell + LN + MLP body (shared by k_gru and k_final) -----------
__device__ __forceinline__ void gru_body(
    int bk, int s, int laneBase, int prep_next,
    float* upd, float* Abuf, float* slots, float* qbuf,
    const float* s_wih, const float* s_whh,
    const float* s_bih, const float* s_bhh,
    const float* s_w1, const float* s_b1,
    const float* s_w2, const float* s_b2,
    const float* s_lnmw, const float* s_lnmb,
    const float* s_lnsw, const float* s_lnsb, const float* s_wq)
{
  float inv = 1.f / Abuf[bk];
  float u[16], h[16];
  #pragma unroll
  for (int j = 0; j < 16; ++j) {
    u[j] = upd[bk*16+j] * inv;
    h[j] = slots[bk*16+j];
  }
  float hs = slots[bk*16+s];

  float gir = s_bih[s],  giz = s_bih[16+s], gin = s_bih[32+s];
  float ghr = s_bhh[s],  ghz = s_bhh[16+s], ghn = s_bhh[32+s];
  #pragma unroll
  for (int j = 0; j < 16; ++j) {
    gir = fmaf(u[j], s_wih[s*17+j], gir);
    giz = fmaf(u[j], s_wih[(16+s)*17+j], giz);
    gin = fmaf(u[j], s_wih[(32+s)*17+j], gin);
    ghr = fmaf(h[j], s_whh[s*17+j], ghr);
    ghz = fmaf(h[j], s_whh[(16+s)*17+j], ghz);
    ghn = fmaf(h[j], s_whh[(32+s)*17+j], ghn);
  }
  float rr = sigmoid_f(gir + ghr);
  float zz = sigmoid_f(giz + ghz);
  float nn = tanh_f(gin + rr*ghn);
  float hn = (1.f-zz)*nn + zz*hs;

  float ssum = hn;
  #pragma unroll
  for (int mm = 1; mm < 16; mm <<= 1) ssum += __shfl_xor(ssum, mm);
  float mu = ssum*(1.f/16.f);
  float dv = hn - mu;
  float vs = dv*dv;
  #pragma unroll
  for (int mm = 1; mm < 16; mm <<= 1) vs += __shfl_xor(vs, mm);
  float rstd = rsqrtf(vs*(1.f/16.f) + 1e-5f);
  float y = dv*rstd*s_lnmw[s] + s_lnmb[s];

  float yv[16];
  #pragma unroll
  for (int j = 0; j < 16; ++j) yv[j] = __shfl(y, laneBase + j);

  float h1[8];
  #pragma unroll
  for (int i = 0; i < 8; ++i) {
    int jj = i*16 + s;
    float a = s_b1[jj];
    #pragma unroll
    for (int q = 0; q < 16; ++q) a = fmaf(yv[q], s_w1[jj*17+q], a);
    h1[i] = fmaxf(a, 0.f);
  }
  float o = s_b2[s];
  #pragma unroll
  for (int i = 0; i < 8; ++i) {
    #pragma unroll
    for (int sp = 0; sp < 16; ++sp) {
      float hv = __shfl(h1[i], laneBase + sp);
      o = fmaf(hv, s_w2[s*129 + i*16 + sp], o);
    }
  }
  float slot_new = hn + o;
  slots[bk*16+s] = slot_new;

  if (prep_next) {
    float ss = slot_new;
    #pragma unroll
    for (int mm = 1; mm < 16; mm <<= 1) ss += __shfl_xor(ss, mm);
    float mu2 = ss*(1.f/16.f);
    float d2 = slot_new - mu2;
    float v2 = d2*d2;
    #pragma unroll
    for (int mm = 1; mm < 16; mm <<= 1) v2 += __shfl_xor(v2, mm);
    float rstd2 = rsqrtf(v2*(1.f/16.f) + 1e-5f);
    float y2 = d2*rstd2*s_lnsw[s] + s_lnsb[s];
    float qv = 0.f;
    #pragma unroll
    for (int sp = 0; sp < 16; ++sp)
      qv = fmaf(__shfl(y2, laneBase+sp), s_wq[s*17+sp], qv);
    qbuf[bk*16+s] = qv;
    upd[bk*16+s] = 0.f;
    if (s == 0) Abuf[bk] = 0.f;
  }
}

#define GRU_STAGE_LDS()                                                      \
  __shared__ float s_wih[48*17], s_whh[48*17];                               \
  __shared__ float s_bih[48], s_bhh[48];                                     \
  __shared__ float s_w1[128*17], s_b1[128];                                  \
  __shared__ float s_w2[16*129], s_b2[16];                                   \
  __shared__ float s_lnmw[16], s_lnmb[16], s_lnsw[16], s_lnsb[16];           \
  __shared__ float s_wq[16*17];                                              \
  {                                                                          \
    int t_ = threadIdx.x;                                                    \
    for (int i = t_; i < 768; i += 256) {                                    \
      int g = i >> 4, j = i & 15;                                            \
      s_wih[g*17+j] = w_ih[i];                                               \
      s_whh[g*17+j] = w_hh[i];                                               \
    }                                                                        \
    for (int i = t_; i < 2048; i += 256) {                                   \
      int r = i >> 4, c = i & 15;                                            \
      s_w1[r*17+c] = mlp_w1[i];                                              \
      int r2 = i >> 7, c2 = i & 127;                                         \
      s_w2[r2*129+c2] = mlp_w2[i];                                           \
    }                                                                        \
    if (t_ < 48) { s_bih[t_] = b_ih[t_]; s_bhh[t_] = b_hh[t_]; }             \
    if (t_ < 128) s_b1[t_] = mlp_b1[t_];                                     \
    if (t_ < 16) {                                                           \
      s_b2[t_] = mlp_b2[t_];                                                 \
      s_lnmw[t_] = ln_m_w[t_]; s_lnmb[t_] = ln_m_b[t_];                      \
      s_lnsw[t_] = ln_s_w[t_]; s_lnsb[t_] = ln_s_b[t_];                      \
    }                                                                        \
    for (int i = t_; i < 256; i += 256) {                                    \
      int r = i >> 4, c = i & 15;                                            \
      s_wq[r*17+c] = wq[i];                                                  \
    }                                                                        \
  }                                                                          \
  __syncthreads();

// ---------------- K3: GRU for iterations 0,1 (16 blocks) -------------------
__global__ __launch_bounds__(256) void k_gru(
    float* __restrict__ upd, float* __restrict__ Abuf,
    float* __restrict__ slots, float* __restrict__ qbuf,
    const float* __restrict__ w_ih, const float* __restrict__ w_hh,
    const float* __restrict__ b_ih, const float* __restrict__ b_hh,
    const float* __restrict__ mlp_w1, const float* __restrict__ mlp_b1,
    const float* __restrict__ mlp_w2, const float* __restrict__ mlp_b2,
    const float* __restrict__ ln_m_w, const float* __restrict__ ln_m_b,
    const float* __restrict__ ln_s_w, const float* __restrict__ ln_s_b,
    const float* __restrict__ wq)
{
  GRU_STAGE_LDS()
  int t = threadIdx.x;
  int bk = blockIdx.x*16 + (t >> 4);
  int s = t & 15;
  int laneBase = (t & 63) & ~15;
  gru_body(bk, s, laneBase, 1, upd, Abuf, slots, qbuf,
           s_wih, s_whh, s_bih, s_bhh, s_w1, s_b1, s_w2, s_b2,
           s_lnmw, s_lnmb, s_lnsw, s_lnsb, s_wq);
}

// ---------------- K4: final GRU (it 2) + attn normalization (fused) --------
__global__ __launch_bounds__(256) void k_final(
    float* __restrict__ upd, float* __restrict__ Abuf,
    float* __restrict__ slots, float* __restrict__ qbuf,
    float* __restrict__ attn,
    const float* __restrict__ w_ih, const float* __restrict__ w_hh,
    const float* __restrict__ b_ih, const float* __restrict__ b_hh,
    const float* __restrict__ mlp_w1, const float* __restrict__ mlp_b1,
    const float* __restrict__ mlp_w2, const float* __restrict__ mlp_b2,
    const float* __restrict__ ln_m_w, const float* __restrict__ ln_m_b,
    const float* __restrict__ ln_s_w, const float* __restrict__ ln_s_b,
    const float* __restrict__ wq)
{
  int t = threadIdx.x;
  {
    int bk = blockIdx.x;
    float inv = 1.f / Abuf[bk];
    float4* p = (float4*)(attn + (size_t)bk*4096);
    #pragma unroll 4
    for (int i = t; i < 1024; i += 256) {
      float4 v = p[i];
      v.x *= inv; v.y *= inv; v.z *= inv; v.w *= inv;
      p[i] = v;
    }
  }
  if (blockIdx.x >= 16) return;
  GRU_STAGE_LDS()
  int bk = blockIdx.x*16 + (t >> 4);
  int s = t & 15;
  int laneBase = (t & 63) & ~15;
  gru_body(bk, s, laneBase, 0, upd, Abuf, slots, qbuf,
           s_wih, s_whh, s_bih, s_bhh, s_w1, s_b1, s_w2, s_b2,
           s_lnmw, s_lnmb, s_lnsw, s_lnsb, s_wq);
}

extern "C" void kernel_launch(void* const* d_in, const int* in_sizes, int n_in,
                              void* d_out, int out_size, void* d_ws, size_t ws_size,
                              hipStream_t stream)
{
  const float* inputs     = (const float*)d_in[0];
  const float* init_slots = (const float*)d_in[1];
  const float* ln_in_w    = (const float*)d_in[2];
  const float* ln_in_b    = (const float*)d_in[3];
  const float* ln_s_w     = (const float*)d_in[4];
  const float* ln_s_b     = (const float*)d_in[5];
  const float* ln_m_w     = (const float*)d_in[6];
  const float* ln_m_b     = (const float*)d_in[7];
  const float* wq         = (const float*)d_in[8];
  const float* wk         = (const float*)d_in[9];
  const float* wv         = (const float*)d_in[10];
  const float* w_ih       = (const float*)d_in[11];
  const float* w_hh       = (const float*)d_in[12];
  const float* b_ih       = (const float*)d_in[13];
  const float* b_hh       = (const float*)d_in[14];
  const float* mlp_w1     = (const float*)d_in[15];
  const float* mlp_b1     = (const float*)d_in[16];
  const float* mlp_w2     = (const float*)d_in[17];
  const float* mlp_b2     = (const float*)d_in[18];

  float* ws    = (float*)d_ws;
  ushort_t* Wh = (ushort_t*)ws;            // 8192 ushorts (16 KB)
  ushort_t* Wl = (ushort_t*)(ws + 4096);   // 8192 ushorts (16 KB)
  float* mt    = ws + 8192;          // 64
  float* qbuf  = ws + 8320;          // 4096
  float* upd   = ws + 12416;         // 4096
  float* Abuf  = ws + 16512;         // 256
  float* kproj = ws + 16768;         // 2097152 floats (8 MB)
  ushort_t* vT = (ushort_t*)(ws + 16768 + 2097152);  // 2 planes x 2M ushorts

  float* out   = (float*)d_out;
  float* slots = out;                // [32,8,16]
  float* attn  = out + 4096;         // [32,8,4096]

  k_prep<<<32, 256, 0, stream>>>(ln_in_w, ln_in_b, wk, wv, init_slots,
                                 ln_s_w, ln_s_b, wq,
                                 Wh, Wl, mt, qbuf, upd, Abuf, slots);
  k_proj<<<2048, 256, 0, stream>>>(inputs, Wh, Wl, mt, kproj, vT);
  for (int it = 0; it < 3; ++it) {
    int last = (it == 2);
    k_attn<<<512, 256, 0, stream>>>(kproj, vT, qbuf, upd, Abuf, attn, last);
    if (!last)
      k_gru<<<16, 256, 0, stream>>>(upd, Abuf, slots, qbuf,
                                    w_ih, w_hh, b_ih, b_hh,
                                    mlp_w1, mlp_b1, mlp_w2, mlp_b2,
                                    ln_m_w, ln_m_b, ln_s_w, ln_s_b, wq);
  }
  k_final<<<256, 256, 0, stream>>>(upd, Abuf, slots, qbuf, attn,
                                   w_ih, w_hh, b_ih, b_hh,
                                   mlp_w1, mlp_b1, mlp_w2, mlp_b2,
                                   ln_m_w, ln_m_b, ln_s_w, ln_s_b, wq);
}